// Round 8
// baseline (427.397 us; speedup 1.0000x reference)
//
#include <hip/hip_runtime.h>

#define NSAMP 8192
#define GSTEP 256
#define SCL   2.8853900817779268f   // 2*log2(e): folded into A1/cf so tanh uses exp2 directly
#define L2E   1.4426950408889634f   // log2(e): applied to q-rows at consumption
#define LN2   0.69314718055994531f
#define LN2DT 0.0069314718055994531f // 0.01*ln2

typedef __attribute__((ext_vector_type(8))) short short8;   // bf16x8 MFMA frag
typedef __attribute__((ext_vector_type(4))) float f32x4;

__device__ __forceinline__ float exp2_hw(float x){ float r; asm("v_exp_f32 %0, %1" : "=v"(r) : "v"(x)); return r; }
__device__ __forceinline__ float log2_hw(float x){ float r; asm("v_log_f32 %0, %1" : "=v"(r) : "v"(x)); return r; }
__device__ __forceinline__ unsigned pk_bf16(float a, float b){ unsigned r; asm("v_cvt_pk_bf16_f32 %0, %1, %2" : "=v"(r) : "v"(a), "v"(b)); return r; }

// tanh(h) given y = 2*log2(e)*h :  1 - 2/(1+2^y)
__device__ __forceinline__ float tanh_scl(float y) {
    float e = exp2_hw(y);
    return fmaf(-2.0f, __builtin_amdgcn_rcpf(1.0f + e), 1.0f);
}
__device__ __forceinline__ float fast_tanh(float x) {   // encoder only
    float e = exp2_hw(x * SCL);
    return fmaf(-2.0f, __builtin_amdgcn_rcpf(1.0f + e), 1.0f);
}

union frag_u { unsigned u[4]; short8 s; };

// split 8 floats (elem-ascending pairs) into hi/lo bf16 fragments
__device__ __forceinline__ void split8(const float* v, short8& H, short8& L) {
    frag_u Hu, Lu;
    #pragma unroll
    for (int r = 0; r < 4; ++r) {
        float a = v[2*r], b = v[2*r+1];
        unsigned h = pk_bf16(a, b);
        float ha = __int_as_float(h << 16);
        float hb = __int_as_float(h & 0xffff0000u);
        Hu.u[r] = h;
        Lu.u[r] = pk_bf16(a - ha, b - hb);
    }
    H = Hu.s; L = Lu.s;
}

__global__ void tmax_k(const float* __restrict__ tstop, float* __restrict__ ws) {
    __shared__ float sm[16];
    float m = -1e30f;
    for (int i = threadIdx.x; i < NSAMP; i += 1024) m = fmaxf(m, tstop[i]);
    #pragma unroll
    for (int o = 32; o > 0; o >>= 1) m = fmaxf(m, __shfl_down(m, o, 64));
    if ((threadIdx.x & 63) == 0) sm[threadIdx.x >> 6] = m;
    __syncthreads();
    if (threadIdx.x == 0) {
        float r = sm[0];
        for (int w = 1; w < 16; ++w) r = fmaxf(r, sm[w]);
        ws[0] = r;
    }
}

__global__ void enc_k(const float* __restrict__ x,
                      const float* __restrict__ eW1, const float* __restrict__ eb1,
                      const float* __restrict__ eW2, const float* __restrict__ eb2,
                      float* __restrict__ zout) {
    int s = blockIdx.x * 256 + threadIdx.x;
    float xv[32];
    #pragma unroll
    for (int i = 0; i < 8; ++i) {
        float4 v = reinterpret_cast<const float4*>(x)[s * 8 + i];
        xv[4*i+0] = v.x; xv[4*i+1] = v.y; xv[4*i+2] = v.z; xv[4*i+3] = v.w;
    }
    float z[32];
    #pragma unroll
    for (int o = 0; o < 32; ++o) z[o] = eb2[o];
    #pragma unroll 4
    for (int h = 0; h < 64; ++h) {
        float a = eb1[h];
        #pragma unroll
        for (int i = 0; i < 32; ++i) a += xv[i] * eW1[i * 64 + h];
        float th = fast_tanh(a);
        #pragma unroll
        for (int o = 0; o < 32; ++o) z[o] += th * eW2[h * 32 + o];
    }
    #pragma unroll
    for (int o = 0; o < 32; ++o) zout[s * 32 + o] = z[o];
}

// Block = 2 waves = 16 samples; wave wv owns hidden tiles 4wv..4wv+3 (64 units).
// L1: 4 tiles x 3 split-MFMAs per wave. L2 partial: 2 chained MFMAs (K=64 slice).
// Cross-wave combine of the 3 q-rows via double-buffered LDS + 1 barrier/step.
// col = l&15 = sample; a = l>>4 = k-group. D layout (m89): row=a*4+reg, col=l&15.
__global__ void __launch_bounds__(128, 1)
surv_k(const float* __restrict__ x,
       const float* __restrict__ tstop,
       const int* __restrict__ fsv, const int* __restrict__ tsv,
       const int* __restrict__ siv, const int* __restrict__ eiv,
       const float* __restrict__ W1, const float* __restrict__ b1,
       const float* __restrict__ W2, const float* __restrict__ b2,
       const float* __restrict__ wsf,
       float* __restrict__ out)
{
    __shared__ __align__(16) float qx[2][2][16][4];   // [buf][wave][sample][slot]
    const int tid = threadIdx.x;
    const int wv  = tid >> 6;           // 0,1
    const int l   = tid & 63;
    const int a   = l >> 4;
    const int col = l & 15;
    const int s   = blockIdx.x * 16 + col;

    // ---- A1 fragments for this wave's 4 tiles (W1 state-rows + t-row, *SCL) ----
    short8 A1h[4], A1l[4];
    #pragma unroll
    for (int tt = 0; tt < 4; ++tt) {
        const int tg = 4 * wv + tt;
        float av[8];
        #pragma unroll
        for (int i = 0; i < 8; ++i) {
            int k = a * 8 + i;
            float v = 0.f;
            if (k < 21) v = W1[k * 128 + tg * 16 + col];
            else if (k == 21) v = W1[85 * 128 + tg * 16 + col];   // t-row
            av[i] = v * SCL;
        }
        split8(av, A1h[tt], A1l[tt]);
    }

    // ---- A2 fragments: W2^T K-slices for this wave (rows 0..2 scaled by L2E) ----
    short8 A2f[2];
    {
        int  cc  = (col < 6) ? col : 0;
        bool cok = (col < 6);
        float csc = (col < 3) ? L2E : 1.0f;
        #pragma unroll
        for (int j = 0; j < 2; ++j) {
            frag_u F;
            #pragma unroll
            for (int rr = 0; rr < 4; ++rr) {
                int e0 = 2 * rr, e1 = e0 + 1;
                int h0 = (2 * wv + j) * 32 + (e0 >> 2) * 16 + a * 4 + (e0 & 3);
                int h1 = (2 * wv + j) * 32 + (e1 >> 2) * 16 + a * 4 + (e1 & 3);
                float w0 = cok ? W2[h0 * 6 + cc] * csc : 0.f;
                float w1 = cok ? W2[h1 * 6 + cc] * csc : 0.f;
                F.u[rr] = pk_bf16(w0, w1);
            }
            A2f[j] = F.s;
        }
    }
    const float sb0 = L2E * b2[0], sb1 = L2E * b2[1], sb2 = L2E * b2[2];

    // ---- c-fold via MFMA: cf = b1 + W1[z-rows]^T z + W1[x-rows]^T x, then *SCL ----
    f32x4 cf[4];
    #pragma unroll
    for (int tt = 0; tt < 4; ++tt) {
        const int tg = 4 * wv + tt;
        cf[tt] = f32x4{ b1[tg*16 + a*4 + 0], b1[tg*16 + a*4 + 1],
                        b1[tg*16 + a*4 + 2], b1[tg*16 + a*4 + 3] };
    }
    {
        const float* zp = wsf + 16 + s * 32;
        const float* xp = x + s * 32;
        #pragma unroll
        for (int j = 0; j < 2; ++j) {
            float bv[8];
            #pragma unroll
            for (int i = 0; i < 8; ++i) bv[i] = (j == 0) ? zp[a*8 + i] : xp[a*8 + i];
            short8 Bh, Bl; split8(bv, Bh, Bl);
            #pragma unroll
            for (int tt = 0; tt < 4; ++tt) {
                const int tg = 4 * wv + tt;
                float av[8];
                #pragma unroll
                for (int i = 0; i < 8; ++i)
                    av[i] = W1[(21 + j*32 + a*8 + i) * 128 + tg * 16 + col];
                short8 Ah, Al; split8(av, Ah, Al);
                cf[tt] = __builtin_amdgcn_mfma_f32_16x16x32_bf16(Ah, Bh, cf[tt], 0,0,0);
                cf[tt] = __builtin_amdgcn_mfma_f32_16x16x32_bf16(Ah, Bl, cf[tt], 0,0,0);
                cf[tt] = __builtin_amdgcn_mfma_f32_16x16x32_bf16(Al, Bh, cf[tt], 0,0,0);
            }
        }
        #pragma unroll
        for (int tt = 0; tt < 4; ++tt)
            #pragma unroll
            for (int r = 0; r < 4; ++r) cf[tt][r] *= SCL;
    }

    // ---- partial net: state(22 incl t) -> this wave's partial D2 rows (f32x4) ----
    auto run_net = [&](const float* hs) -> f32x4 {
        float sv[8];
        #pragma unroll
        for (int i = 0; i < 8; ++i) {
            float x01 = (a == 0) ? hs[i] : hs[8 + i];
            float x2  = (i < 6) ? hs[16 + i] : 0.f;
            sv[i] = (a < 2) ? x01 : ((a == 2) ? x2 : 0.f);
        }
        short8 Bh, Bl; split8(sv, Bh, Bl);
        f32x4 acc[4];
        #pragma unroll
        for (int tt = 0; tt < 4; ++tt) {
            acc[tt] = cf[tt];
            acc[tt] = __builtin_amdgcn_mfma_f32_16x16x32_bf16(A1h[tt], Bh, acc[tt], 0,0,0);
            acc[tt] = __builtin_amdgcn_mfma_f32_16x16x32_bf16(A1h[tt], Bl, acc[tt], 0,0,0);
            acc[tt] = __builtin_amdgcn_mfma_f32_16x16x32_bf16(A1l[tt], Bh, acc[tt], 0,0,0);
        }
        f32x4 a2 = {0.f, 0.f, 0.f, 0.f};
        #pragma unroll
        for (int j = 0; j < 2; ++j) {
            frag_u F;
            #pragma unroll
            for (int rr = 0; rr < 4; ++rr) {
                int tile = 2 * j + (rr >> 1);
                int r0 = 2 * (rr & 1);
                F.u[rr] = pk_bf16(tanh_scl(acc[tile][r0]), tanh_scl(acc[tile][r0 + 1]));
            }
            a2 = __builtin_amdgcn_mfma_f32_16x16x32_bf16(A2f[j], F.s, a2, 0,0,0);
        }
        return a2;
    };

    const int si = siv[s], ei = eiv[s];

    float st[22];
    #pragma unroll
    for (int k = 0; k < 22; ++k) st[k] = 0.f;
    st[0] = st[4] = st[8] = 1.f;          // P = I
    st[9] = st[13] = st[17] = 1.f;        // Tinv = I
    float Tsnap[9], Ssnap[21];
    #pragma unroll
    for (int k = 0; k < 9; ++k) Tsnap[k] = 0.f;
    #pragma unroll
    for (int k = 0; k < 21; ++k) Ssnap[k] = 0.f;

    int buf = 0;
    for (int m = 0; m < GSTEP; ++m) {
        if (__any((m == si) || (m == ei))) {
            if (m == si) {
                #pragma unroll
                for (int k = 0; k < 9; ++k) Tsnap[k] = st[9 + k];
            }
            if (m == ei) {
                #pragma unroll
                for (int k = 0; k < 21; ++k) Ssnap[k] = st[k];
            }
        }
        st[21] = (float)m * 0.01f;

        f32x4 a2 = run_net(st);
        if (l < 16)   // rows 0..2 of this wave's partial D2 (a==0, regs 0..2)
            *reinterpret_cast<float4*>(&qx[buf][wv][col][0]) =
                make_float4(a2[0], a2[1], a2[2], 0.f);
        __syncthreads();
        float4 pA = *reinterpret_cast<const float4*>(&qx[buf][0][col][0]);
        float4 pB = *reinterpret_cast<const float4*>(&qx[buf][1][col][0]);
        buf ^= 1;
        float q0d = LN2DT * log2_hw(1.0f + exp2_hw(pA.x + pB.x + sb0));
        float q1d = LN2DT * log2_hw(1.0f + exp2_hw(pA.y + pB.y + sb1));
        float q2d = LN2DT * log2_hw(1.0f + exp2_hw(pA.z + pB.z + sb2));
        float qsd = q0d + q1d;

        #pragma unroll
        for (int i = 0; i < 3; ++i) {
            float Pi0 = st[3*i], Pi1 = st[3*i+1];
            st[3*i+0] = fmaf(-qsd, Pi0, st[3*i+0]);
            st[3*i+1] = fmaf(-q2d, Pi1, fmaf(q0d, Pi0, st[3*i+1]));
            st[3*i+2] = fmaf( q2d, Pi1, fmaf(q1d, Pi0, st[3*i+2]));
        }
        #pragma unroll
        for (int k = 0; k < 3; ++k) {
            float T0 = st[9+k], T1 = st[12+k], T2 = st[15+k];
            st[9+k]  = fmaf(-q1d, T2, fmaf(-q0d, T1, fmaf(qsd, T0, st[9+k])));
            st[12+k] = fmaf(q2d, T1 - T2, st[12+k]);
        }
        st[18] += q0d; st[19] += q1d; st[20] += q2d;
    }
    if (ei == GSTEP) {
        #pragma unroll
        for (int k = 0; k < 21; ++k) Ssnap[k] = st[k];
    }

    // ---- epilogue: e1 (state@tstop: q rows 0..2), e2 (final state: rows 3..5) ----
    __syncthreads();    // make last-step qx reads safe against reuse below

    float h1[22];
    #pragma unroll
    for (int k = 0; k < 21; ++k) h1[k] = Ssnap[k];
    h1[21] = tstop[s];
    f32x4 e1 = run_net(h1);
    if (l < 16)
        *reinterpret_cast<float4*>(&qx[0][wv][col][0]) =
            make_float4(e1[0], e1[1], e1[2], 0.f);

    float h2[22];
    #pragma unroll
    for (int k = 0; k < 21; ++k) h2[k] = st[k];
    h2[21] = wsf[0];
    f32x4 e2 = run_net(h2);
    // rows 3..5 of e2: row3 = (a==0,reg3), row4 = (a==1,reg0), row5 = (a==1,reg1)
    if (a == 0) qx[1][wv][col][0] = e2[3];
    if (a == 1) { qx[1][wv][col][1] = e2[0]; qx[1][wv][col][2] = e2[1]; }
    __syncthreads();

    float ya = qx[0][0][col][0] + qx[0][1][col][0] + sb0;
    float yb = qx[0][0][col][1] + qx[0][1][col][1] + sb1;
    float yc = qx[0][0][col][2] + qx[0][1][col][2] + sb2;
    float qv0 = LN2 * log2_hw(1.0f + exp2_hw(ya));
    float qv1 = LN2 * log2_hw(1.0f + exp2_hw(yb));
    float qv2 = LN2 * log2_hw(1.0f + exp2_hw(yc));
    float hz3 = qx[1][0][col][0] + qx[1][1][col][0] + b2[3];
    float hz4 = qx[1][0][col][1] + qx[1][1][col][1] + b2[4];
    float hz5 = qx[1][0][col][2] + qx[1][1][col][2] + b2[5];

    int fi = fsv[s] - 1;
    int ti = tsv[s] - 1;
    float Sv = 0.f;
    #pragma unroll
    for (int j = 0; j < 3; ++j)
        Sv = fmaf(Tsnap[fi * 3 + j], Ssnap[3 * j + fi], Sv);
    float lam = (fi == 0) ? ((ti == 1) ? qv0 : ((ti == 2) ? qv1 : 0.0f))
                          : ((fi == 1 && ti == 2) ? qv2 : 0.0f);

    if (wv == 0 && l < 16) {
        out[s]                     = Sv;
        out[NSAMP + s]             = lam;
        out[2 * NSAMP + 3 * s + 0] = hz3;
        out[2 * NSAMP + 3 * s + 1] = hz4;
        out[2 * NSAMP + 3 * s + 2] = hz5;
    }
}

extern "C" void kernel_launch(void* const* d_in, const int* in_sizes, int n_in,
                              void* d_out, int out_size, void* d_ws, size_t ws_size,
                              hipStream_t stream) {
    const float* x     = (const float*)d_in[0];
    const float* tstop = (const float*)d_in[2];
    const int*   fs    = (const int*)d_in[3];
    const int*   ts    = (const int*)d_in[4];
    const int*   si    = (const int*)d_in[5];
    const int*   ei    = (const int*)d_in[6];
    const float* eW1   = (const float*)d_in[10];
    const float* eb1   = (const float*)d_in[11];
    const float* eW2   = (const float*)d_in[12];
    const float* eb2   = (const float*)d_in[13];
    const float* W1    = (const float*)d_in[14];
    const float* b1    = (const float*)d_in[15];
    const float* W2    = (const float*)d_in[16];
    const float* b2    = (const float*)d_in[17];
    float* wsf = (float*)d_ws;
    float* out = (float*)d_out;

    tmax_k<<<1, 1024, 0, stream>>>(tstop, wsf);
    enc_k<<<32, 256, 0, stream>>>(x, eW1, eb1, eW2, eb2, wsf + 16);
    surv_k<<<512, 128, 0, stream>>>(x, tstop, fs, ts, si, ei,
                                    W1, b1, W2, b2, wsf, out);
}

// Round 11
// 380.447 us; speedup vs baseline: 1.1234x; 1.1234x over previous
//
#include <hip/hip_runtime.h>

#define NSAMP 8192
#define GSTEP 256
#define SCL   2.8853900817779268f   // 2*log2(e): folded into A1/cf so exp2(acc)=e^{2h}
#define L2E   1.4426950408889634f   // log2(e): folded into W2n q-cols
#define LN2   0.69314718055994531f
#define LN2DT 0.0069314718055994531f // 0.01*ln2

typedef __attribute__((ext_vector_type(8))) short short8;   // bf16x8 MFMA frag
typedef __attribute__((ext_vector_type(4))) float f32x4;

__device__ __forceinline__ float exp2_hw(float x){ float r; asm("v_exp_f32 %0, %1" : "=v"(r) : "v"(x)); return r; }
__device__ __forceinline__ float log2_hw(float x){ float r; asm("v_log_f32 %0, %1" : "=v"(r) : "v"(x)); return r; }
__device__ __forceinline__ unsigned pk_bf16(float a, float b){ unsigned r; asm("v_cvt_pk_bf16_f32 %0, %1, %2" : "=v"(r) : "v"(a), "v"(b)); return r; }

// u = 1/(1+e^{2h}) given y = SCL*h ; tanh(h) = 1 - 2u (the -2 is folded into W2n)
__device__ __forceinline__ float u_of(float y) {
    return __builtin_amdgcn_rcpf(1.0f + exp2_hw(y));
}
__device__ __forceinline__ float fast_tanh(float x) {   // encoder only
    float e = exp2_hw(x * SCL);
    return fmaf(-2.0f, __builtin_amdgcn_rcpf(1.0f + e), 1.0f);
}

union frag_u { unsigned u[4]; short8 s; };

// split 8 floats (elem-ascending pairs) into hi/lo bf16 fragments
__device__ __forceinline__ void split8(const float* v, short8& H, short8& L) {
    frag_u Hu, Lu;
    #pragma unroll
    for (int r = 0; r < 4; ++r) {
        float a = v[2*r], b = v[2*r+1];
        unsigned h = pk_bf16(a, b);
        float ha = __int_as_float(h << 16);
        float hb = __int_as_float(h & 0xffff0000u);
        Hu.u[r] = h;
        Lu.u[r] = pk_bf16(a - ha, b - hb);
    }
    H = Hu.s; L = Lu.s;
}

__global__ void tmax_k(const float* __restrict__ tstop, float* __restrict__ ws) {
    __shared__ float sm[16];
    float m = -1e30f;
    for (int i = threadIdx.x; i < NSAMP; i += 1024) m = fmaxf(m, tstop[i]);
    #pragma unroll
    for (int o = 32; o > 0; o >>= 1) m = fmaxf(m, __shfl_down(m, o, 64));
    if ((threadIdx.x & 63) == 0) sm[threadIdx.x >> 6] = m;
    __syncthreads();
    if (threadIdx.x == 0) {
        float r = sm[0];
        for (int w = 1; w < 16; ++w) r = fmaxf(r, sm[w]);
        ws[0] = r;
    }
}

__global__ void enc_k(const float* __restrict__ x,
                      const float* __restrict__ eW1, const float* __restrict__ eb1,
                      const float* __restrict__ eW2, const float* __restrict__ eb2,
                      float* __restrict__ zout) {
    int s = blockIdx.x * 256 + threadIdx.x;
    float xv[32];
    #pragma unroll
    for (int i = 0; i < 8; ++i) {
        float4 v = reinterpret_cast<const float4*>(x)[s * 8 + i];
        xv[4*i+0] = v.x; xv[4*i+1] = v.y; xv[4*i+2] = v.z; xv[4*i+3] = v.w;
    }
    float z[32];
    #pragma unroll
    for (int o = 0; o < 32; ++o) z[o] = eb2[o];
    #pragma unroll 4
    for (int h = 0; h < 64; ++h) {
        float a = eb1[h];
        #pragma unroll
        for (int i = 0; i < 32; ++i) a += xv[i] * eW1[i * 64 + h];
        float th = fast_tanh(a);
        #pragma unroll
        for (int o = 0; o < 32; ++o) z[o] += th * eW2[h * 32 + o];
    }
    #pragma unroll
    for (int o = 0; o < 32; ++o) zout[s * 32 + o] = z[o];
}

// ONE wave = 16 samples, all 128 hidden units, no LDS, no barriers (r7-proven).
// col = l&15 = sample; a = l>>4 = k-group. L1: 8 tiles x 3 split-MFMAs.
// L2 on VALU: lane holds 32 tanh-args of ITS sample (D rows for col) -> 96 fmaf
// with W2n = -2*L2E*W2, rowsum folded into SB; shfl_xor(16,32) -> q in ALL lanes.
__global__ void __launch_bounds__(64, 1)
surv_k(const float* __restrict__ x,
       const float* __restrict__ tstop,
       const int* __restrict__ fsv, const int* __restrict__ tsv,
       const int* __restrict__ siv, const int* __restrict__ eiv,
       const float* __restrict__ W1, const float* __restrict__ b1,
       const float* __restrict__ W2, const float* __restrict__ b2,
       const float* __restrict__ wsf,
       float* __restrict__ out)
{
    const int l   = threadIdx.x;
    const int a   = l >> 4;
    const int col = l & 15;
    const int s   = blockIdx.x * 16 + col;

    // ---- A1 fragments (W1 state-rows + t-row, scaled by SCL), hi/lo ----
    short8 A1h[8], A1l[8];
    #pragma unroll
    for (int tt = 0; tt < 8; ++tt) {
        float av[8];
        #pragma unroll
        for (int i = 0; i < 8; ++i) {
            int k = a * 8 + i;
            float v = 0.f;
            if (k < 21) v = W1[k * 128 + tt * 16 + col];
            else if (k == 21) v = W1[85 * 128 + tt * 16 + col];   // t-row
            av[i] = v * SCL;
        }
        split8(av, A1h[tt], A1l[tt]);
    }

    // ---- in-loop W2 (q-cols, -2*L2E folded) at this lane's D rows; rowsums ----
    float W2n[8][4][3];
    float rs0 = 0.f, rs1 = 0.f, rs2 = 0.f, rs3 = 0.f, rs4 = 0.f, rs5 = 0.f;
    #pragma unroll
    for (int tt = 0; tt < 8; ++tt)
        #pragma unroll
        for (int r = 0; r < 4; ++r) {
            int jd = tt * 16 + a * 4 + r;
            float w0 = W2[jd * 6 + 0], w1 = W2[jd * 6 + 1], w2 = W2[jd * 6 + 2];
            rs0 += w0; rs1 += w1; rs2 += w2;
            rs3 += W2[jd * 6 + 3]; rs4 += W2[jd * 6 + 4]; rs5 += W2[jd * 6 + 5];
            W2n[tt][r][0] = -2.f * L2E * w0;
            W2n[tt][r][1] = -2.f * L2E * w1;
            W2n[tt][r][2] = -2.f * L2E * w2;
        }
    // reduce rowsums over a-groups (one-time)
    rs0 += __shfl_xor(rs0, 16, 64); rs0 += __shfl_xor(rs0, 32, 64);
    rs1 += __shfl_xor(rs1, 16, 64); rs1 += __shfl_xor(rs1, 32, 64);
    rs2 += __shfl_xor(rs2, 16, 64); rs2 += __shfl_xor(rs2, 32, 64);
    rs3 += __shfl_xor(rs3, 16, 64); rs3 += __shfl_xor(rs3, 32, 64);
    rs4 += __shfl_xor(rs4, 16, 64); rs4 += __shfl_xor(rs4, 32, 64);
    rs5 += __shfl_xor(rs5, 16, 64); rs5 += __shfl_xor(rs5, 32, 64);
    const float SB0 = L2E * (b2[0] + rs0);   // softplus arg bias (L2E-scaled)
    const float SB1 = L2E * (b2[1] + rs1);
    const float SB2 = L2E * (b2[2] + rs2);
    const float SBe3 = b2[3] + rs3;          // raw bias for hazard rows
    const float SBe4 = b2[4] + rs4;
    const float SBe5 = b2[5] + rs5;

    // ---- c-fold via MFMA: cf = b1 + W1[z-rows]^T z + W1[x-rows]^T x, then *SCL ----
    f32x4 cf[8];
    #pragma unroll
    for (int tt = 0; tt < 8; ++tt) {
        cf[tt] = f32x4{ b1[tt*16 + a*4 + 0], b1[tt*16 + a*4 + 1],
                        b1[tt*16 + a*4 + 2], b1[tt*16 + a*4 + 3] };
    }
    {
        const float* zp = wsf + 16 + s * 32;
        const float* xp = x + s * 32;
        #pragma unroll
        for (int j = 0; j < 2; ++j) {
            float bv[8];
            #pragma unroll
            for (int i = 0; i < 8; ++i) bv[i] = (j == 0) ? zp[a*8 + i] : xp[a*8 + i];
            short8 Bh, Bl; split8(bv, Bh, Bl);
            #pragma unroll
            for (int tt = 0; tt < 8; ++tt) {
                float av[8];
                #pragma unroll
                for (int i = 0; i < 8; ++i)
                    av[i] = W1[(21 + j*32 + a*8 + i) * 128 + tt * 16 + col];
                short8 Ah, Al; split8(av, Ah, Al);
                cf[tt] = __builtin_amdgcn_mfma_f32_16x16x32_bf16(Ah, Bh, cf[tt], 0,0,0);
                cf[tt] = __builtin_amdgcn_mfma_f32_16x16x32_bf16(Ah, Bl, cf[tt], 0,0,0);
                cf[tt] = __builtin_amdgcn_mfma_f32_16x16x32_bf16(Al, Bh, cf[tt], 0,0,0);
            }
        }
        #pragma unroll
        for (int tt = 0; tt < 8; ++tt)
            #pragma unroll
            for (int r = 0; r < 4; ++r) cf[tt][r] *= SCL;
    }

    // ---- L1: state(22 incl t) -> acc[8] (y = SCL*logit per unit) ----
    auto run_l1 = [&](const float* hs, f32x4* acc) {
        float sv[8];
        #pragma unroll
        for (int i = 0; i < 8; ++i) {
            float x01 = (a == 0) ? hs[i] : hs[8 + i];
            float x2  = (i < 6) ? hs[16 + i] : 0.f;
            sv[i] = (a < 2) ? x01 : ((a == 2) ? x2 : 0.f);
        }
        short8 Bh, Bl; split8(sv, Bh, Bl);
        #pragma unroll
        for (int tt = 0; tt < 8; ++tt) {
            acc[tt] = cf[tt];
            acc[tt] = __builtin_amdgcn_mfma_f32_16x16x32_bf16(A1h[tt], Bh, acc[tt], 0,0,0);
            acc[tt] = __builtin_amdgcn_mfma_f32_16x16x32_bf16(A1h[tt], Bl, acc[tt], 0,0,0);
            acc[tt] = __builtin_amdgcn_mfma_f32_16x16x32_bf16(A1l[tt], Bh, acc[tt], 0,0,0);
        }
    };

    const int si = siv[s], ei = eiv[s];

    float st[22];
    #pragma unroll
    for (int k = 0; k < 22; ++k) st[k] = 0.f;
    st[0] = st[4] = st[8] = 1.f;          // P = I
    st[9] = st[13] = st[17] = 1.f;        // Tinv = I
    float Tsnap[9], Ssnap[21];
    #pragma unroll
    for (int k = 0; k < 9; ++k) Tsnap[k] = 0.f;
    #pragma unroll
    for (int k = 0; k < 21; ++k) Ssnap[k] = 0.f;

    for (int m = 0; m < GSTEP; ++m) {
        if (__any((m == si) || (m == ei))) {
            if (m == si) {
                #pragma unroll
                for (int k = 0; k < 9; ++k) Tsnap[k] = st[9 + k];
            }
            if (m == ei) {
                #pragma unroll
                for (int k = 0; k < 21; ++k) Ssnap[k] = st[k];
            }
        }
        st[21] = (float)m * 0.01f;

        f32x4 acc[8];
        run_l1(st, acc);
        // VALU L2: u = rcp(1+exp2(y)); p_c = Σ u * (-2*L2E*W2); rowsum in SB
        float p0 = 0.f, p1 = 0.f, p2 = 0.f;
        #pragma unroll
        for (int tt = 0; tt < 8; ++tt)
            #pragma unroll
            for (int r = 0; r < 4; ++r) {
                float u = u_of(acc[tt][r]);
                p0 = fmaf(u, W2n[tt][r][0], p0);
                p1 = fmaf(u, W2n[tt][r][1], p1);
                p2 = fmaf(u, W2n[tt][r][2], p2);
            }
        p0 += __shfl_xor(p0, 16, 64); p0 += __shfl_xor(p0, 32, 64);
        p1 += __shfl_xor(p1, 16, 64); p1 += __shfl_xor(p1, 32, 64);
        p2 += __shfl_xor(p2, 16, 64); p2 += __shfl_xor(p2, 32, 64);
        float q0d = LN2DT * log2_hw(1.0f + exp2_hw(p0 + SB0));   // dt*softplus
        float q1d = LN2DT * log2_hw(1.0f + exp2_hw(p1 + SB1));
        float q2d = LN2DT * log2_hw(1.0f + exp2_hw(p2 + SB2));
        float qsd = q0d + q1d;

        #pragma unroll
        for (int i = 0; i < 3; ++i) {
            float Pi0 = st[3*i], Pi1 = st[3*i+1];
            st[3*i+0] = fmaf(-qsd, Pi0, st[3*i+0]);
            st[3*i+1] = fmaf(-q2d, Pi1, fmaf(q0d, Pi0, st[3*i+1]));
            st[3*i+2] = fmaf( q2d, Pi1, fmaf(q1d, Pi0, st[3*i+2]));
        }
        #pragma unroll
        for (int k = 0; k < 3; ++k) {
            float T0 = st[9+k], T1 = st[12+k], T2 = st[15+k];
            st[9+k]  = fmaf(-q1d, T2, fmaf(-q0d, T1, fmaf(qsd, T0, st[9+k])));
            st[12+k] = fmaf(q2d, T1 - T2, st[12+k]);
        }
        st[18] += q0d; st[19] += q1d; st[20] += q2d;
    }
    if (ei == GSTEP) {
        #pragma unroll
        for (int k = 0; k < 21; ++k) Ssnap[k] = st[k];
    }

    // ---- epilogue e1: state at tstop -> q rows 0..2 (same VALU path) ----
    float h1[22];
    #pragma unroll
    for (int k = 0; k < 21; ++k) h1[k] = Ssnap[k];
    h1[21] = tstop[s];
    float qv0, qv1, qv2;
    {
        f32x4 acc[8];
        run_l1(h1, acc);
        float p0 = 0.f, p1 = 0.f, p2 = 0.f;
        #pragma unroll
        for (int tt = 0; tt < 8; ++tt)
            #pragma unroll
            for (int r = 0; r < 4; ++r) {
                float u = u_of(acc[tt][r]);
                p0 = fmaf(u, W2n[tt][r][0], p0);
                p1 = fmaf(u, W2n[tt][r][1], p1);
                p2 = fmaf(u, W2n[tt][r][2], p2);
            }
        p0 += __shfl_xor(p0, 16, 64); p0 += __shfl_xor(p0, 32, 64);
        p1 += __shfl_xor(p1, 16, 64); p1 += __shfl_xor(p1, 32, 64);
        p2 += __shfl_xor(p2, 16, 64); p2 += __shfl_xor(p2, 32, 64);
        qv0 = LN2 * log2_hw(1.0f + exp2_hw(p0 + SB0));
        qv1 = LN2 * log2_hw(1.0f + exp2_hw(p1 + SB1));
        qv2 = LN2 * log2_hw(1.0f + exp2_hw(p2 + SB2));
    }

    // ---- epilogue e2: final state at t=max(tstop) -> hazard rows 3..5 ----
    float h2[22];
    #pragma unroll
    for (int k = 0; k < 21; ++k) h2[k] = st[k];
    h2[21] = wsf[0];
    float hz3, hz4, hz5;
    {
        f32x4 acc[8];
        run_l1(h2, acc);
        float p3 = 0.f, p4 = 0.f, p5 = 0.f;
        #pragma unroll
        for (int tt = 0; tt < 8; ++tt)
            #pragma unroll
            for (int r = 0; r < 4; ++r) {
                int jd = tt * 16 + a * 4 + r;
                float u = u_of(acc[tt][r]);
                p3 = fmaf(u, -2.f * W2[jd * 6 + 3], p3);
                p4 = fmaf(u, -2.f * W2[jd * 6 + 4], p4);
                p5 = fmaf(u, -2.f * W2[jd * 6 + 5], p5);
            }
        p3 += __shfl_xor(p3, 16, 64); p3 += __shfl_xor(p3, 32, 64);
        p4 += __shfl_xor(p4, 16, 64); p4 += __shfl_xor(p4, 32, 64);
        p5 += __shfl_xor(p5, 16, 64); p5 += __shfl_xor(p5, 32, 64);
        hz3 = p3 + SBe3;
        hz4 = p4 + SBe4;
        hz5 = p5 + SBe5;
    }

    int fi = fsv[s] - 1;
    int ti = tsv[s] - 1;
    float Sv = 0.f;
    #pragma unroll
    for (int j = 0; j < 3; ++j)
        Sv = fmaf(Tsnap[fi * 3 + j], Ssnap[3 * j + fi], Sv);
    float lam = (fi == 0) ? ((ti == 1) ? qv0 : ((ti == 2) ? qv1 : 0.0f))
                          : ((fi == 1 && ti == 2) ? qv2 : 0.0f);

    if (l < 16) {
        out[s]                     = Sv;
        out[NSAMP + s]             = lam;
        out[2 * NSAMP + 3 * s + 0] = hz3;
        out[2 * NSAMP + 3 * s + 1] = hz4;
        out[2 * NSAMP + 3 * s + 2] = hz5;
    }
}

extern "C" void kernel_launch(void* const* d_in, const int* in_sizes, int n_in,
                              void* d_out, int out_size, void* d_ws, size_t ws_size,
                              hipStream_t stream) {
    const float* x     = (const float*)d_in[0];
    const float* tstop = (const float*)d_in[2];
    const int*   fs    = (const int*)d_in[3];
    const int*   ts    = (const int*)d_in[4];
    const int*   si    = (const int*)d_in[5];
    const int*   ei    = (const int*)d_in[6];
    const float* eW1   = (const float*)d_in[10];
    const float* eb1   = (const float*)d_in[11];
    const float* eW2   = (const float*)d_in[12];
    const float* eb2   = (const float*)d_in[13];
    const float* W1    = (const float*)d_in[14];
    const float* b1    = (const float*)d_in[15];
    const float* W2    = (const float*)d_in[16];
    const float* b2    = (const float*)d_in[17];
    float* wsf = (float*)d_ws;
    float* out = (float*)d_out;

    tmax_k<<<1, 1024, 0, stream>>>(tstop, wsf);
    enc_k<<<32, 256, 0, stream>>>(x, eW1, eb1, eW2, eb2, wsf + 16);
    surv_k<<<512, 64, 0, stream>>>(x, tstop, fs, ts, si, ei,
                                   W1, b1, W2, b2, wsf, out);
}